// Round 4
// baseline (694.355 us; speedup 1.0000x reference)
//
#include <hip/hip_runtime.h>

// layer_3d_dep_53300544143949 — MI355X (gfx950)
// B=64, C=8, O=8, M=32, K=32, NR=8, NT=8. All inputs and output FLOAT32.
// R3 structure:
//   K1: stats-zero + a2pre[b,o,krt] = 0.1 * P2 (x) mean_m(A)   (meanM never materialized)
//   K2: main fold + attention; pre-BN out -> bf16 ws (or f32 d_out fallback); stats atomics
//   K3: BN normalize (bf16 ws -> f32 d_out, or in-place f32)
// ws layout: [0,256) stats | [256, 256+4MB) a2pre f32 | [+4MB, +4MB+67MB) xb bf16 (optional)

using u16 = unsigned short;
using u32 = unsigned int;

__device__ __forceinline__ void ld8f(const float* p, float* f) {
  float4 a = *(const float4*)p;
  float4 b = *(const float4*)(p + 4);
  f[0] = a.x; f[1] = a.y; f[2] = a.z; f[3] = a.w;
  f[4] = b.x; f[5] = b.y; f[6] = b.z; f[7] = b.w;
}
__device__ __forceinline__ void st8f(float* p, const float* f) {
  *(float4*)p = make_float4(f[0], f[1], f[2], f[3]);
  *(float4*)(p + 4) = make_float4(f[4], f[5], f[6], f[7]);
}
__device__ __forceinline__ u16 f2b(float f) {
  u32 x = __float_as_uint(f);
  x += 0x7fffu + ((x >> 16) & 1u);   // RNE
  return (u16)(x >> 16);
}
__device__ __forceinline__ float b2f(u16 h) {
  return __uint_as_float(((u32)h) << 16);
}
__device__ __forceinline__ float fast_tanh(float x) {
  float e = __expf(2.0f * x);
  return 1.0f - 2.0f / (e + 1.0f);
}

// ---------------- K1: stats zero + a2pre ----------------
// grid 512 = b*8+kq; 256 thr; thread owns krt column j = kq*256+tid.
__global__ __launch_bounds__(256, 4) void k1_a2pre(
    const float* __restrict__ A, const float* __restrict__ P2,
    float* __restrict__ a2pre, float* __restrict__ stats) {
  const int b = blockIdx.x >> 3;
  const int kq = blockIdx.x & 7;
  const int tid = threadIdx.x;
  if (blockIdx.x == 0 && tid < 16) stats[tid] = 0.0f;
  const int j = kq * 256 + tid;
  float mc[8];
#pragma unroll
  for (int c = 0; c < 8; ++c) {
    const float* base = A + ((size_t)(b * 8 + c) * 65536 + j);
    float s = 0.0f;
#pragma unroll
    for (int m = 0; m < 32; ++m) s += base[m * 2048];
    mc[c] = s * (1.0f / 32.0f);
  }
#pragma unroll
  for (int o = 0; o < 8; ++o) {
    float a2 = 0.0f;
#pragma unroll
    for (int c = 0; c < 8; ++c) a2 = fmaf(P2[o * 8 + c], mc[c], a2);
    a2pre[(size_t)(b * 8 + o) * 2048 + j] = 0.1f * a2;
  }
}

// ---------------- K2: main ----------------
// grid 2048 = (b<<5)|m; 256 thr. (k,r): k=tid>>3, r=tid&7 (r = lane bits 0..2).
template <bool BF16OUT>
__global__ __launch_bounds__(256, 4) void k2_main(
    const float* __restrict__ A,
    const float* __restrict__ a2pre,
    const float* __restrict__ P1,
    const float* __restrict__ P3,
    const float* __restrict__ P4,
    const float* __restrict__ P5,
    const float* __restrict__ Wq,
    const float* __restrict__ Wk,
    float* __restrict__ outp,      // used when !BF16OUT
    u16* __restrict__ xb,          // used when BF16OUT
    float* __restrict__ stats) {
  __shared__ float qb[8 * 260];
  __shared__ float kb[8 * 260];
  __shared__ float vb[8 * 260];
  __shared__ float a5b[8 * 260];
  __shared__ float sred[64];

  const int tid = threadIdx.x;
  const int b = blockIdx.x >> 5;
  const int m = blockIdx.x & 31;
  const int k = tid >> 3;
  const int r = tid & 7;

  float acc[8][8];
  float qv[8], kv[8], vv[8];
#pragma unroll
  for (int o = 0; o < 8; ++o)
#pragma unroll
    for (int t = 0; t < 8; ++t) acc[o][t] = 0.0f;
#pragma unroll
  for (int t = 0; t < 8; ++t) { qv[t] = 0.0f; kv[t] = 0.0f; vv[t] = 0.0f; }

  // Single c-loop: load A row; tr_c via lane-xor means; fold A1/A3/A4; accumulate qkv.
#pragma unroll
  for (int c = 0; c < 8; ++c) {
    float ar[8];
    ld8f(A + ((size_t)((b * 8 + c) * 32 + m) * 2048 + tid * 8), ar);
    float trc[8];
#pragma unroll
    for (int t = 0; t < 8; ++t) {
      float x = ar[t];
      x += __shfl_xor(x, 1, 64);
      x += __shfl_xor(x, 2, 64);
      x += __shfl_xor(x, 4, 64);
      trc[t] = x * 0.125f;
    }
    const float mtc = (ar[0] + ar[1] + ar[2] + ar[3] +
                       ar[4] + ar[5] + ar[6] + ar[7]) * 0.125f;
#pragma unroll
    for (int o = 0; o < 8; ++o) {
      const float w1 = P1[o * 8 + c];
      const float w4 = 0.5f * P4[o * 8 + c];
      const float w3 = 0.1f * P3[o * 8 + c];
#pragma unroll
      for (int t = 0; t < 8; ++t)
        acc[o][t] = fmaf(w1, ar[t], fmaf(w4, trc[t], fmaf(w3, mtc, acc[o][t])));
    }
    const float wq = Wq[r * 8 + c];
    const float wk = Wk[r * 8 + c];
    const float wv = P5[r * 8 + c];
#pragma unroll
    for (int t = 0; t < 8; ++t) {
      qv[t] = fmaf(wq, trc[t], qv[t]);
      kv[t] = fmaf(wk, trc[t], kv[t]);
      vv[t] = fmaf(wv, trc[t], vv[t]);
    }
  }

  // A2: precomputed 0.1*P2(x)meanM, m-independent
#pragma unroll
  for (int o = 0; o < 8; ++o) {
    float a2v[8];
    ld8f(a2pre + ((size_t)(b * 8 + o) * 2048 + tid * 8), a2v);
#pragma unroll
    for (int t = 0; t < 8; ++t) acc[o][t] += a2v[t];
  }

  st8f(&qb[r * 260 + k * 8], qv);
  st8f(&kb[r * 260 + k * 8], kv);
  st8f(&vb[r * 260 + k * 8], vv);
  __syncthreads();

  // Attention: thread = (o, kq, lo): 4 k-rows x 8 l-rows register tile
  {
    const int o = tid >> 5;
    const int kq = (tid >> 2) & 7;
    const int lo = tid & 3;
    float qf[4][8];
#pragma unroll
    for (int kl = 0; kl < 4; ++kl)
      ld8f(&qb[o * 260 + (kq * 4 + kl) * 8], qf[kl]);
    float a5p[4][8];
#pragma unroll
    for (int kl = 0; kl < 4; ++kl)
#pragma unroll
      for (int t = 0; t < 8; ++t) a5p[kl][t] = 0.0f;

#pragma unroll
    for (int ll = 0; ll < 8; ++ll) {
      const int l = lo * 8 + ll;
      float krw[8];
      ld8f(&kb[o * 260 + l * 8], krw);
      float al[4];
#pragma unroll
      for (int kl = 0; kl < 4; ++kl) {
        float s = 0.0f;
#pragma unroll
        for (int t = 0; t < 8; ++t) s = fmaf(qf[kl][t], krw[t], s);
        al[kl] = fast_tanh(s * 0.125f);  // /NT
      }
      float vrw[8];
      ld8f(&vb[o * 260 + l * 8], vrw);
#pragma unroll
      for (int kl = 0; kl < 4; ++kl)
#pragma unroll
        for (int t = 0; t < 8; ++t)
          a5p[kl][t] = fmaf(al[kl], vrw[t], a5p[kl][t]);
    }
#pragma unroll
    for (int kl = 0; kl < 4; ++kl)
#pragma unroll
      for (int t = 0; t < 8; ++t) {
        float x = a5p[kl][t];
        x += __shfl_xor(x, 1, 64);
        x += __shfl_xor(x, 2, 64);
        a5p[kl][t] = x * 0.0625f;  // 2/Kd
      }
#pragma unroll
    for (int kl = 0; kl < 4; ++kl) {
      const float w0 = lo == 0 ? a5p[kl][0] : lo == 1 ? a5p[kl][2]
                      : lo == 2 ? a5p[kl][4] : a5p[kl][6];
      const float w1 = lo == 0 ? a5p[kl][1] : lo == 1 ? a5p[kl][3]
                      : lo == 2 ? a5p[kl][5] : a5p[kl][7];
      *(float2*)&a5b[o * 260 + (kq * 4 + kl) * 8 + lo * 2] = make_float2(w0, w1);
    }
  }
  __syncthreads();

  // Epilogue: +A5, ReLU, stats, store pre-BN
  float psum[8], psq[8];
#pragma unroll
  for (int o = 0; o < 8; ++o) { psum[o] = 0.0f; psq[o] = 0.0f; }
  const size_t outbase = (size_t)(b * 256 + m) * 2048 + tid * 8;
#pragma unroll
  for (int o = 0; o < 8; ++o) {
    float a5f[8];
    ld8f(&a5b[o * 260 + k * 8], a5f);
    float x8[8];
#pragma unroll
    for (int t = 0; t < 8; ++t) {
      float x = acc[o][t] + a5f[t];
      x = fmaxf(x, 0.0f);
      psum[o] += x;
      psq[o] = fmaf(x, x, psq[o]);
      x8[t] = x;
    }
    if (BF16OUT) {
      uint4 u;
      u.x = (u32)f2b(x8[0]) | ((u32)f2b(x8[1]) << 16);
      u.y = (u32)f2b(x8[2]) | ((u32)f2b(x8[3]) << 16);
      u.z = (u32)f2b(x8[4]) | ((u32)f2b(x8[5]) << 16);
      u.w = (u32)f2b(x8[6]) | ((u32)f2b(x8[7]) << 16);
      *(uint4*)(xb + (outbase + (size_t)o * 65536)) = u;
    } else {
      st8f(outp + (outbase + (size_t)o * 65536), x8);
    }
  }
  // stats: wave butterfly -> LDS -> 16 global atomics
#pragma unroll
  for (int o = 0; o < 8; ++o) {
    float s = psum[o], q = psq[o];
#pragma unroll
    for (int mask = 32; mask >= 1; mask >>= 1) {
      s += __shfl_xor(s, mask, 64);
      q += __shfl_xor(q, mask, 64);
    }
    psum[o] = s; psq[o] = q;
  }
  const int lane = tid & 63;
  const int wid = tid >> 6;
  if (lane == 0) {
#pragma unroll
    for (int o = 0; o < 8; ++o) {
      sred[wid * 16 + o * 2] = psum[o];
      sred[wid * 16 + o * 2 + 1] = psq[o];
    }
  }
  __syncthreads();
  if (tid < 16) {
    float s = sred[tid] + sred[16 + tid] + sred[32 + tid] + sred[48 + tid];
    atomicAdd(&stats[tid], s);
  }
}

// ---------------- K3a: BN in place (f32 d_out) ----------------
__global__ void k3_norm_inplace(float* __restrict__ outp,
                                const float* __restrict__ stats,
                                const float* __restrict__ gamma,
                                const float* __restrict__ beta) {
  const int idx = blockIdx.x * 256 + threadIdx.x;
  const size_t e0 = (size_t)idx * 8;
  const int o = (int)(e0 >> 16) & 7;
  const float N = 4194304.0f;
  const float mean = stats[o * 2] / N;
  float var = stats[o * 2 + 1] / N - mean * mean;
  var = fmaxf(var, 0.0f);
  const float inv = rsqrtf(var + 1e-5f);
  const float g = gamma[o] * inv;
  const float sh = beta[o] - mean * g;
  float f[8];
  ld8f(outp + e0, f);
#pragma unroll
  for (int t = 0; t < 8; ++t) f[t] = fmaf(f[t], g, sh);
  st8f(outp + e0, f);
}

// ---------------- K3b: BN from bf16 staging -> f32 d_out ----------------
__global__ void k3_norm_bf16(const u16* __restrict__ xb,
                             float* __restrict__ outp,
                             const float* __restrict__ stats,
                             const float* __restrict__ gamma,
                             const float* __restrict__ beta) {
  const int idx = blockIdx.x * 256 + threadIdx.x;
  const size_t e0 = (size_t)idx * 8;
  const int o = (int)(e0 >> 16) & 7;
  const float N = 4194304.0f;
  const float mean = stats[o * 2] / N;
  float var = stats[o * 2 + 1] / N - mean * mean;
  var = fmaxf(var, 0.0f);
  const float inv = rsqrtf(var + 1e-5f);
  const float g = gamma[o] * inv;
  const float sh = beta[o] - mean * g;
  const uint4 u = *(const uint4*)(xb + e0);
  float f[8];
  f[0] = b2f((u16)(u.x & 0xffffu)); f[1] = b2f((u16)(u.x >> 16));
  f[2] = b2f((u16)(u.y & 0xffffu)); f[3] = b2f((u16)(u.y >> 16));
  f[4] = b2f((u16)(u.z & 0xffffu)); f[5] = b2f((u16)(u.z >> 16));
  f[6] = b2f((u16)(u.w & 0xffffu)); f[7] = b2f((u16)(u.w >> 16));
#pragma unroll
  for (int t = 0; t < 8; ++t) f[t] = fmaf(f[t], g, sh);
  st8f(outp + e0, f);
}

extern "C" void kernel_launch(void* const* d_in, const int* in_sizes, int n_in,
                              void* d_out, int out_size, void* d_ws, size_t ws_size,
                              hipStream_t stream) {
  const float* A  = (const float*)d_in[0];
  const float* P1 = (const float*)d_in[1];
  const float* P2 = (const float*)d_in[2];
  const float* P3 = (const float*)d_in[3];
  const float* P4 = (const float*)d_in[4];
  const float* P5 = (const float*)d_in[5];
  const float* Wq = (const float*)d_in[6];
  const float* Wk = (const float*)d_in[7];
  const float* gamma = (const float*)d_in[8];
  const float* beta  = (const float*)d_in[9];
  float* outp = (float*)d_out;

  float* stats = (float*)d_ws;
  float* a2pre = (float*)((char*)d_ws + 256);
  u16* xb = (u16*)((char*)d_ws + 256 + (size_t)4 * 1024 * 1024);
  const size_t need_bf16 = 256 + (size_t)4 * 1024 * 1024 + (size_t)67108864;
  const bool use_bf16 = (ws_size >= need_bf16);

  hipLaunchKernelGGL(k1_a2pre, dim3(512), dim3(256), 0, stream, A, P2, a2pre, stats);
  if (use_bf16) {
    hipLaunchKernelGGL((k2_main<true>), dim3(2048), dim3(256), 0, stream,
                       A, a2pre, P1, P3, P4, P5, Wq, Wk, outp, xb, stats);
    hipLaunchKernelGGL(k3_norm_bf16, dim3(16384), dim3(256), 0, stream,
                       xb, outp, stats, gamma, beta);
  } else {
    hipLaunchKernelGGL((k2_main<false>), dim3(2048), dim3(256), 0, stream,
                       A, a2pre, P1, P3, P4, P5, Wq, Wk, outp, xb, stats);
    hipLaunchKernelGGL(k3_norm_inplace, dim3(16384), dim3(256), 0, stream,
                       outp, stats, gamma, beta);
  }
}

// Round 5
// 380.482 us; speedup vs baseline: 1.8249x; 1.8249x over previous
//
#include <hip/hip_runtime.h>

// layer_3d_dep_53300544143949 — MI355X (gfx950)
// B=64, C=8, O=8, M=32, K=32, NR=8, NT=8. All inputs and output FLOAT32.
// R4 structure (R3 structure, spill fix + A3 hoist):
//   K1: stats-zero + a2pre[b,o,krt] = 0.1 * P2 (x) mean_m(A)
//   K2: main fold + attention; pre-BN -> bf16 ws (or f32 d_out); stats atomics
//       __launch_bounds__(256,2): (256,4) forced VGPR 128->64 and spilled ~1.2GB
//       to scratch (R3 post-mortem: FETCH 566MB, WRITE 968MB, dur 471us).
//   K3: BN normalize (bf16 ws -> f32 d_out, or in-place f32)
// ws: [0,256) stats | [256, 256+4MB) a2pre f32 | [+4MB, +67MB) xb bf16 (optional)

using u16 = unsigned short;
using u32 = unsigned int;

__device__ __forceinline__ void ld8f(const float* p, float* f) {
  float4 a = *(const float4*)p;
  float4 b = *(const float4*)(p + 4);
  f[0] = a.x; f[1] = a.y; f[2] = a.z; f[3] = a.w;
  f[4] = b.x; f[5] = b.y; f[6] = b.z; f[7] = b.w;
}
__device__ __forceinline__ void st8f(float* p, const float* f) {
  *(float4*)p = make_float4(f[0], f[1], f[2], f[3]);
  *(float4*)(p + 4) = make_float4(f[4], f[5], f[6], f[7]);
}
__device__ __forceinline__ u16 f2b(float f) {
  u32 x = __float_as_uint(f);
  x += 0x7fffu + ((x >> 16) & 1u);   // RNE
  return (u16)(x >> 16);
}
__device__ __forceinline__ float b2f(u16 h) {
  return __uint_as_float(((u32)h) << 16);
}
__device__ __forceinline__ float fast_tanh(float x) {
  float e = __expf(2.0f * x);
  return 1.0f - 2.0f / (e + 1.0f);
}

// ---------------- K1: stats zero + a2pre ----------------
// grid 512 = b*8+kq; 256 thr; thread owns krt column j = kq*256+tid.
__global__ void k1_a2pre(
    const float* __restrict__ A, const float* __restrict__ P2,
    float* __restrict__ a2pre, float* __restrict__ stats) {
  const int b = blockIdx.x >> 3;
  const int kq = blockIdx.x & 7;
  const int tid = threadIdx.x;
  if (blockIdx.x == 0 && tid < 16) stats[tid] = 0.0f;
  const int j = kq * 256 + tid;
  float mc[8];
#pragma unroll
  for (int c = 0; c < 8; ++c) {
    const float* base = A + ((size_t)(b * 8 + c) * 65536 + j);
    float s = 0.0f;
#pragma unroll
    for (int m = 0; m < 32; ++m) s += base[m * 2048];
    mc[c] = s * (1.0f / 32.0f);
  }
#pragma unroll
  for (int o = 0; o < 8; ++o) {
    float a2 = 0.0f;
#pragma unroll
    for (int c = 0; c < 8; ++c) a2 = fmaf(P2[o * 8 + c], mc[c], a2);
    a2pre[(size_t)(b * 8 + o) * 2048 + j] = 0.1f * a2;
  }
}

// ---------------- K2: main ----------------
// grid 2048 = (b<<5)|m; 256 thr. (k,r): k=tid>>3, r=tid&7 (r = lane bits 0..2).
template <bool BF16OUT>
__global__ __launch_bounds__(256, 2) void k2_main(
    const float* __restrict__ A,
    const float* __restrict__ a2pre,
    const float* __restrict__ P1,
    const float* __restrict__ P3,
    const float* __restrict__ P4,
    const float* __restrict__ P5,
    const float* __restrict__ Wq,
    const float* __restrict__ Wk,
    float* __restrict__ outp,      // used when !BF16OUT
    u16* __restrict__ xb,          // used when BF16OUT
    float* __restrict__ stats) {
  __shared__ float qb[8 * 260];
  __shared__ float kb[8 * 260];
  __shared__ float vb[8 * 260];
  __shared__ float a5b[8 * 260];
  __shared__ float sred[64];

  const int tid = threadIdx.x;
  const int b = blockIdx.x >> 5;
  const int m = blockIdx.x & 31;
  const int k = tid >> 3;
  const int r = tid & 7;

  float acc[8][8];
  float acc3[8];
  float qv[8], kv[8], vv[8];
#pragma unroll
  for (int o = 0; o < 8; ++o) {
    acc3[o] = 0.0f;
#pragma unroll
    for (int t = 0; t < 8; ++t) acc[o][t] = 0.0f;
  }
#pragma unroll
  for (int t = 0; t < 8; ++t) { qv[t] = 0.0f; kv[t] = 0.0f; vv[t] = 0.0f; }

  // Single c-loop: load A row; trc via lane-xor means; fold A1/A4 per-t,
  // A3 hoisted to scalar acc3[o]; accumulate qkv (o = r lane mapping).
#pragma unroll
  for (int c = 0; c < 8; ++c) {
    float ar[8];
    ld8f(A + ((size_t)((b * 8 + c) * 32 + m) * 2048 + tid * 8), ar);
    float trc[8];
#pragma unroll
    for (int t = 0; t < 8; ++t) {
      float x = ar[t];
      x += __shfl_xor(x, 1, 64);
      x += __shfl_xor(x, 2, 64);
      x += __shfl_xor(x, 4, 64);
      trc[t] = x * 0.125f;
    }
    const float mtc = (ar[0] + ar[1] + ar[2] + ar[3] +
                       ar[4] + ar[5] + ar[6] + ar[7]) * 0.125f;
#pragma unroll
    for (int o = 0; o < 8; ++o) {
      const float w1 = P1[o * 8 + c];
      const float w4 = 0.5f * P4[o * 8 + c];
      acc3[o] = fmaf(0.1f * P3[o * 8 + c], mtc, acc3[o]);
#pragma unroll
      for (int t = 0; t < 8; ++t)
        acc[o][t] = fmaf(w1, ar[t], fmaf(w4, trc[t], acc[o][t]));
    }
    const float wq = Wq[r * 8 + c];
    const float wk = Wk[r * 8 + c];
    const float wv = P5[r * 8 + c];
#pragma unroll
    for (int t = 0; t < 8; ++t) {
      qv[t] = fmaf(wq, trc[t], qv[t]);
      kv[t] = fmaf(wk, trc[t], kv[t]);
      vv[t] = fmaf(wv, trc[t], vv[t]);
    }
  }

  // A2 (precomputed, m-independent) + A3 broadcast
#pragma unroll
  for (int o = 0; o < 8; ++o) {
    float a2v[8];
    ld8f(a2pre + ((size_t)(b * 8 + o) * 2048 + tid * 8), a2v);
#pragma unroll
    for (int t = 0; t < 8; ++t) acc[o][t] += a2v[t] + acc3[o];
  }

  st8f(&qb[r * 260 + k * 8], qv);
  st8f(&kb[r * 260 + k * 8], kv);
  st8f(&vb[r * 260 + k * 8], vv);
  __syncthreads();

  // Attention: thread = (o, kq, lo): 4 k-rows x 8 l-rows register tile
  {
    const int o = tid >> 5;
    const int kq = (tid >> 2) & 7;
    const int lo = tid & 3;
    float qf[4][8];
#pragma unroll
    for (int kl = 0; kl < 4; ++kl)
      ld8f(&qb[o * 260 + (kq * 4 + kl) * 8], qf[kl]);
    float a5p[4][8];
#pragma unroll
    for (int kl = 0; kl < 4; ++kl)
#pragma unroll
      for (int t = 0; t < 8; ++t) a5p[kl][t] = 0.0f;

#pragma unroll
    for (int ll = 0; ll < 8; ++ll) {
      const int l = lo * 8 + ll;
      float krw[8];
      ld8f(&kb[o * 260 + l * 8], krw);
      float al[4];
#pragma unroll
      for (int kl = 0; kl < 4; ++kl) {
        float s = 0.0f;
#pragma unroll
        for (int t = 0; t < 8; ++t) s = fmaf(qf[kl][t], krw[t], s);
        al[kl] = fast_tanh(s * 0.125f);  // /NT
      }
      float vrw[8];
      ld8f(&vb[o * 260 + l * 8], vrw);
#pragma unroll
      for (int kl = 0; kl < 4; ++kl)
#pragma unroll
        for (int t = 0; t < 8; ++t)
          a5p[kl][t] = fmaf(al[kl], vrw[t], a5p[kl][t]);
    }
#pragma unroll
    for (int kl = 0; kl < 4; ++kl)
#pragma unroll
      for (int t = 0; t < 8; ++t) {
        float x = a5p[kl][t];
        x += __shfl_xor(x, 1, 64);
        x += __shfl_xor(x, 2, 64);
        a5p[kl][t] = x * 0.0625f;  // 2/Kd
      }
#pragma unroll
    for (int kl = 0; kl < 4; ++kl) {
      const float w0 = lo == 0 ? a5p[kl][0] : lo == 1 ? a5p[kl][2]
                      : lo == 2 ? a5p[kl][4] : a5p[kl][6];
      const float w1 = lo == 0 ? a5p[kl][1] : lo == 1 ? a5p[kl][3]
                      : lo == 2 ? a5p[kl][5] : a5p[kl][7];
      *(float2*)&a5b[o * 260 + (kq * 4 + kl) * 8 + lo * 2] = make_float2(w0, w1);
    }
  }
  __syncthreads();

  // Epilogue: +A5, ReLU, stats, store pre-BN
  float psum[8], psq[8];
#pragma unroll
  for (int o = 0; o < 8; ++o) { psum[o] = 0.0f; psq[o] = 0.0f; }
  const size_t outbase = (size_t)(b * 256 + m) * 2048 + tid * 8;
#pragma unroll
  for (int o = 0; o < 8; ++o) {
    float a5f[8];
    ld8f(&a5b[o * 260 + k * 8], a5f);
    float x8[8];
#pragma unroll
    for (int t = 0; t < 8; ++t) {
      float x = acc[o][t] + a5f[t];
      x = fmaxf(x, 0.0f);
      psum[o] += x;
      psq[o] = fmaf(x, x, psq[o]);
      x8[t] = x;
    }
    if (BF16OUT) {
      uint4 u;
      u.x = (u32)f2b(x8[0]) | ((u32)f2b(x8[1]) << 16);
      u.y = (u32)f2b(x8[2]) | ((u32)f2b(x8[3]) << 16);
      u.z = (u32)f2b(x8[4]) | ((u32)f2b(x8[5]) << 16);
      u.w = (u32)f2b(x8[6]) | ((u32)f2b(x8[7]) << 16);
      *(uint4*)(xb + (outbase + (size_t)o * 65536)) = u;
    } else {
      st8f(outp + (outbase + (size_t)o * 65536), x8);
    }
  }
  // stats: wave butterfly -> LDS -> 16 global atomics
#pragma unroll
  for (int o = 0; o < 8; ++o) {
    float s = psum[o], q = psq[o];
#pragma unroll
    for (int mask = 32; mask >= 1; mask >>= 1) {
      s += __shfl_xor(s, mask, 64);
      q += __shfl_xor(q, mask, 64);
    }
    psum[o] = s; psq[o] = q;
  }
  const int lane = tid & 63;
  const int wid = tid >> 6;
  if (lane == 0) {
#pragma unroll
    for (int o = 0; o < 8; ++o) {
      sred[wid * 16 + o * 2] = psum[o];
      sred[wid * 16 + o * 2 + 1] = psq[o];
    }
  }
  __syncthreads();
  if (tid < 16) {
    float s = sred[tid] + sred[16 + tid] + sred[32 + tid] + sred[48 + tid];
    atomicAdd(&stats[tid], s);
  }
}

// ---------------- K3a: BN in place (f32 d_out) ----------------
__global__ void k3_norm_inplace(float* __restrict__ outp,
                                const float* __restrict__ stats,
                                const float* __restrict__ gamma,
                                const float* __restrict__ beta) {
  const int idx = blockIdx.x * 256 + threadIdx.x;
  const size_t e0 = (size_t)idx * 8;
  const int o = (int)(e0 >> 16) & 7;
  const float N = 4194304.0f;
  const float mean = stats[o * 2] / N;
  float var = stats[o * 2 + 1] / N - mean * mean;
  var = fmaxf(var, 0.0f);
  const float inv = rsqrtf(var + 1e-5f);
  const float g = gamma[o] * inv;
  const float sh = beta[o] - mean * g;
  float f[8];
  ld8f(outp + e0, f);
#pragma unroll
  for (int t = 0; t < 8; ++t) f[t] = fmaf(f[t], g, sh);
  st8f(outp + e0, f);
}

// ---------------- K3b: BN from bf16 staging -> f32 d_out ----------------
__global__ void k3_norm_bf16(const u16* __restrict__ xb,
                             float* __restrict__ outp,
                             const float* __restrict__ stats,
                             const float* __restrict__ gamma,
                             const float* __restrict__ beta) {
  const int idx = blockIdx.x * 256 + threadIdx.x;
  const size_t e0 = (size_t)idx * 8;
  const int o = (int)(e0 >> 16) & 7;
  const float N = 4194304.0f;
  const float mean = stats[o * 2] / N;
  float var = stats[o * 2 + 1] / N - mean * mean;
  var = fmaxf(var, 0.0f);
  const float inv = rsqrtf(var + 1e-5f);
  const float g = gamma[o] * inv;
  const float sh = beta[o] - mean * g;
  const uint4 u = *(const uint4*)(xb + e0);
  float f[8];
  f[0] = b2f((u16)(u.x & 0xffffu)); f[1] = b2f((u16)(u.x >> 16));
  f[2] = b2f((u16)(u.y & 0xffffu)); f[3] = b2f((u16)(u.y >> 16));
  f[4] = b2f((u16)(u.z & 0xffffu)); f[5] = b2f((u16)(u.z >> 16));
  f[6] = b2f((u16)(u.w & 0xffffu)); f[7] = b2f((u16)(u.w >> 16));
#pragma unroll
  for (int t = 0; t < 8; ++t) f[t] = fmaf(f[t], g, sh);
  st8f(outp + e0, f);
}

extern "C" void kernel_launch(void* const* d_in, const int* in_sizes, int n_in,
                              void* d_out, int out_size, void* d_ws, size_t ws_size,
                              hipStream_t stream) {
  const float* A  = (const float*)d_in[0];
  const float* P1 = (const float*)d_in[1];
  const float* P2 = (const float*)d_in[2];
  const float* P3 = (const float*)d_in[3];
  const float* P4 = (const float*)d_in[4];
  const float* P5 = (const float*)d_in[5];
  const float* Wq = (const float*)d_in[6];
  const float* Wk = (const float*)d_in[7];
  const float* gamma = (const float*)d_in[8];
  const float* beta  = (const float*)d_in[9];
  float* outp = (float*)d_out;

  float* stats = (float*)d_ws;
  float* a2pre = (float*)((char*)d_ws + 256);
  u16* xb = (u16*)((char*)d_ws + 256 + (size_t)4 * 1024 * 1024);
  const size_t need_bf16 = 256 + (size_t)4 * 1024 * 1024 + (size_t)67108864;
  const bool use_bf16 = (ws_size >= need_bf16);

  hipLaunchKernelGGL(k1_a2pre, dim3(512), dim3(256), 0, stream, A, P2, a2pre, stats);
  if (use_bf16) {
    hipLaunchKernelGGL((k2_main<true>), dim3(2048), dim3(256), 0, stream,
                       A, a2pre, P1, P3, P4, P5, Wq, Wk, outp, xb, stats);
    hipLaunchKernelGGL(k3_norm_bf16, dim3(16384), dim3(256), 0, stream,
                       xb, outp, stats, gamma, beta);
  } else {
    hipLaunchKernelGGL((k2_main<false>), dim3(2048), dim3(256), 0, stream,
                       A, a2pre, P1, P3, P4, P5, Wq, Wk, outp, xb, stats);
    hipLaunchKernelGGL(k3_norm_inplace, dim3(16384), dim3(256), 0, stream,
                       outp, stats, gamma, beta);
  }
}